// Round 10
// baseline (415.129 us; speedup 1.0000x reference)
//
#include <hip/hip_runtime.h>
#include <hip/hip_bf16.h>

typedef unsigned short u16;
typedef unsigned int u32;
typedef __attribute__((ext_vector_type(2))) float f32x2;
typedef __attribute__((ext_vector_type(4))) float f32x4;
typedef __attribute__((ext_vector_type(4))) u16 u16x4;
typedef __attribute__((ext_vector_type(8))) u16 u16x8;
typedef __attribute__((ext_vector_type(8))) __bf16 bf16x8;

#define B_ 32
#define T_ 2048
#define MID_ 1024
#define TOPIC_ 512
#define H_ 256
#define ROWS_ 32
#define NCH_ (T_ / ROWS_)   // 64 chunks per batch
#define CPW_ 8              // chunks per workgroup (grid 256 = 1 WG/CU)

// fp32 -> bf16 RNE
static __device__ __forceinline__ u16 f2bf(float x) {
    u32 u = __float_as_uint(x);
    u = (u + 0x7FFFu + ((u >> 16) & 1u)) >> 16;
    return (u16)u;
}
static __device__ __forceinline__ float bf2f(u32 lo16) {
    return __uint_as_float(lo16 << 16);
}

// ---------------- merged prep ----------------
// blocks 0..255 : Wa row h=blk -> bf16 into layout
//   wa16s[ks:32][tt:16][kgrp:4][rl:16][j:8]  (u16 idx = ks*8192 + tt*512 + kgrp*128 + rl*8 + j)
// blocks 256..287 : enc_out[b][h];  block 288 : vsum.
__global__ __launch_bounds__(256) void k_prep(const float* __restrict__ enc,
                                              const float* __restrict__ Ua_w,
                                              const float* __restrict__ Ua_b,
                                              const float* __restrict__ Wa,
                                              const float* __restrict__ v_w,
                                              float* __restrict__ enc_out,
                                              u16* __restrict__ wa16s,
                                              float* __restrict__ vsum) {
    __shared__ float es[TOPIC_];
    const int blk = blockIdx.x, tid = threadIdx.x;
    if (blk < 256) {
        const int h = blk, k = tid * 4;
        f32x4 w = *(const f32x4*)(Wa + h * MID_ + k);
        u16x4 h4;
        h4[0] = f2bf(w[0]); h4[1] = f2bf(w[1]); h4[2] = f2bf(w[2]); h4[3] = f2bf(w[3]);
        const int tt = h >> 4, rl = h & 15;
        const int ks = k >> 5, kg = (k >> 3) & 3, j = k & 7;
        *(u16x4*)&wa16s[ks * 8192 + tt * 512 + kg * 128 + rl * 8 + j] = h4;
    } else if (blk < 288) {
        const int b = blk - 256;
        es[tid]       = enc[b * TOPIC_ + tid];
        es[tid + 256] = enc[b * TOPIC_ + 256 + tid];
        __syncthreads();
        const float* ua = Ua_w + (size_t)tid * TOPIC_;
        float s = Ua_b[tid];
        #pragma unroll 4
        for (int d = 0; d < TOPIC_; d += 4) {
            f32x4 u = *(const f32x4*)(ua + d);
            s += u[0] * es[d] + u[1] * es[d + 1] + u[2] * es[d + 2] + u[3] * es[d + 3];
        }
        enc_out[b * H_ + tid] = s;
    } else {
        if (tid < 64) {
            const int lane = tid;
            float s = v_w[lane] + v_w[lane + 64] + v_w[lane + 128] + v_w[lane + 192];
            #pragma unroll
            for (int m = 32; m; m >>= 1) s += __shfl_xor(s, m, 64);
            if (lane == 0) *vsum = s;
        }
    }
}

// ---------------- fused single-pass, As-double-buffered chunk pipeline ----------------
// grid 256 (1 WG/CU, persistent), 512 threads = 8 waves; each WG: 8 contiguous chunks
// of one batch row. Per iteration c: [BARt] [convert st -> As[p^1] (chunk c+1; its
// loads issued a full iteration ago -> wait ~0)] [issue st <- chunk c+2] [round-8
// barrier-free K-loop on As[p]] [partc, BAR1, softmax, BAR2, wsum from As[p]].
// All barrier vmcnt-drains are free (in-flight loads always >1 iteration old).
// __launch_bounds__(512,2): VGPR cap 256 -> st[16]+ring fit with NO spill (r9 fix).
__global__ __launch_bounds__(512, 2) void k_fused(const float* __restrict__ dec,
                                                  const int* __restrict__ masks,
                                                  const float* __restrict__ enc_out,
                                                  const float* __restrict__ v_w,
                                                  const float* __restrict__ vsum_p,
                                                  const u16* __restrict__ wa16s,
                                                  float* __restrict__ po,
                                                  float* __restrict__ pms) {
    __shared__ __attribute__((aligned(16))) u16 As[2][ROWS_ * MID_];  // 128 KB
    __shared__ float partc[8][ROWS_];
    __shared__ float ev[ROWS_];

    const int tid = threadIdx.x;
    const int lane = tid & 63, wave = tid >> 6;
    const int rl = lane & 15, kgrp = lane >> 4;
    const int wg = blockIdx.x;                 // 0..255
    const int b = wg >> 3;                     // 8 WGs per batch row
    const int cbase = (wg & 7) * CPW_;         // contiguous 8-chunk span

    // enc/v per-lane registers (this wave's 32 cols)
    float encr[2], vr[2];
    #pragma unroll
    for (int ct = 0; ct < 2; ++ct) {
        const int h = wave * 32 + ct * 16 + rl;
        encr[ct] = enc_out[b * H_ + h];
        vr[ct] = v_w[h];
    }

    // constant bases (round-8 K-loop)
    const u16* bb = wa16s + wave * 1024 + kgrp * 128 + rl * 8;  // +ct*512 +ks*8192
    const int ar0 = rl * MID_,        k0 = rl << 3;
    const int ar1 = (16 + rl) * MID_, k1 = (16 + rl) << 3;
    const int kstart = wave * 4;               // per-wave rotated K order

    f32x4 st[16];   // staging regs: granule g = tid + i*512 (row=g>>7, colg=g&127)

    #define ISSUE(CI)                                                             \
        do {                                                                      \
            const float* base_ = dec + (size_t)(b * T_ + (CI) * ROWS_) * MID_;    \
            _Pragma("unroll") for (int i_ = 0; i_ < 8; ++i_) {                    \
                const int g_ = tid + i_ * 512;                                    \
                const float* sp_ = base_ + (size_t)(g_ >> 7) * MID_ + (g_ & 127) * 8; \
                st[2 * i_]     = *(const f32x4*)(sp_);                            \
                st[2 * i_ + 1] = *(const f32x4*)(sp_ + 4);                        \
            }                                                                     \
        } while (0)

    #define CONVERT(P)                                                            \
        do {                                                                      \
            _Pragma("unroll") for (int i_ = 0; i_ < 8; ++i_) {                    \
                const int g_ = tid + i_ * 512;                                    \
                const int row_ = g_ >> 7, colg_ = g_ & 127;                       \
                u16x8 h8_;                                                        \
                _Pragma("unroll") for (int e_ = 0; e_ < 4; ++e_) {                \
                    h8_[e_]     = f2bf(st[2 * i_][e_]);                           \
                    h8_[4 + e_] = f2bf(st[2 * i_ + 1][e_]);                       \
                }                                                                 \
                *(u16x8*)&As[P][row_ * MID_ + ((colg_ * 8) ^ (row_ << 3))] = h8_; \
            }                                                                     \
        } while (0)

    // ---- prologue: chunk 0 -> As[0]; chunk 1 loads in flight ----
    ISSUE(cbase);
    CONVERT(0);
    ISSUE(cbase + 1);

    #pragma unroll 1
    for (int c = 0; c < CPW_; ++c) {
        const int chunk = cbase + c;
        const int p = c & 1;
        const int grow = b * T_ + chunk * ROWS_;

        __syncthreads();   // BARt: As[p] converts visible; prior wsum of As[p^1] done

        // ---- convert chunk c+1 into the other buffer (st loads are 1 iter old) ----
        if (c + 1 < CPW_) CONVERT(p ^ 1);
        // ---- issue chunk c+2's staging loads (land during K-loop + epilogue) ----
        if (c + 2 < CPW_) ISSUE(cbase + c + 2);

        // ---- round-8 barrier-free fully-unrolled K-loop on As[p] ----
        f32x4 acc[2][2];
        const f32x4 z = {0.f, 0.f, 0.f, 0.f};
        acc[0][0] = z; acc[0][1] = z; acc[1][0] = z; acc[1][1] = z;

        bf16x8 br0[2], br1[2], br2[2], br3[2];
        {
            const int s0 = kstart, s1 = (kstart + 1) & 31;
            const int s2 = (kstart + 2) & 31, s3 = (kstart + 3) & 31;
            br0[0] = *(const bf16x8*)(bb + s0 * 8192);
            br0[1] = *(const bf16x8*)(bb + s0 * 8192 + 512);
            br1[0] = *(const bf16x8*)(bb + s1 * 8192);
            br1[1] = *(const bf16x8*)(bb + s1 * 8192 + 512);
            br2[0] = *(const bf16x8*)(bb + s2 * 8192);
            br2[1] = *(const bf16x8*)(bb + s2 * 8192 + 512);
            br3[0] = *(const bf16x8*)(bb + s3 * 8192);
            br3[1] = *(const bf16x8*)(bb + s3 * 8192 + 512);
        }
        bf16x8 afc0 = *(const bf16x8*)&As[p][ar0 + ((kstart * 32 + kgrp * 8) ^ k0)];
        bf16x8 afc1 = *(const bf16x8*)&As[p][ar1 + ((kstart * 32 + kgrp * 8) ^ k1)];

        #pragma unroll
        for (int i = 0; i < 32; ++i) {
            bf16x8 an0 = afc0, an1 = afc1;
            if (i < 31) {
                const int ksn = (kstart + i + 1) & 31;
                an0 = *(const bf16x8*)&As[p][ar0 + ((ksn * 32 + kgrp * 8) ^ k0)];
                an1 = *(const bf16x8*)&As[p][ar1 + ((ksn * 32 + kgrp * 8) ^ k1)];
            }
            {
                bf16x8* brc = ((i & 3) == 0) ? br0 : ((i & 3) == 1) ? br1
                             : ((i & 3) == 2) ? br2 : br3;
                acc[0][0] = __builtin_amdgcn_mfma_f32_16x16x32_bf16(afc0, brc[0], acc[0][0], 0, 0, 0);
                acc[1][0] = __builtin_amdgcn_mfma_f32_16x16x32_bf16(afc1, brc[0], acc[1][0], 0, 0, 0);
                acc[0][1] = __builtin_amdgcn_mfma_f32_16x16x32_bf16(afc0, brc[1], acc[0][1], 0, 0, 0);
                acc[1][1] = __builtin_amdgcn_mfma_f32_16x16x32_bf16(afc1, brc[1], acc[1][1], 0, 0, 0);
                if (i < 28) {
                    const int ksp = (kstart + i + 4) & 31;
                    brc[0] = *(const bf16x8*)(bb + ksp * 8192);
                    brc[1] = *(const bf16x8*)(bb + ksp * 8192 + 512);
                }
            }
            afc0 = an0; afc1 = an1;
        }

        // ---- logits partials ----
        float part[2][4];
        #pragma unroll
        for (int rt = 0; rt < 2; ++rt)
            #pragma unroll
            for (int j = 0; j < 4; ++j) {
                float pp = 0.f;
                #pragma unroll
                for (int ct = 0; ct < 2; ++ct)
                    pp += vr[ct] * tanhf(encr[ct] + acc[rt][ct][j]);
                part[rt][j] = pp;
            }
        #pragma unroll
        for (int m = 1; m < 16; m <<= 1)
            #pragma unroll
            for (int rt = 0; rt < 2; ++rt)
                #pragma unroll
                for (int j = 0; j < 4; ++j)
                    part[rt][j] += __shfl_xor(part[rt][j], m, 64);
        if (rl == 0) {
            #pragma unroll
            for (int rt = 0; rt < 2; ++rt)
                #pragma unroll
                for (int j = 0; j < 4; ++j)
                    partc[wave][rt * 16 + kgrp * 4 + j] = part[rt][j];
        }
        __syncthreads();   // BAR1 (st loads for c+2 are ~K-loop old -> drain free)

        // ---- chunk softmax (32 rows; wave 0) ----
        if (wave == 0) {
            const int r = lane & 31;
            float a = 0.f;
            #pragma unroll
            for (int w = 0; w < 8; ++w) a += partc[w][r];
            const int mk = masks[grow + r];
            a = mk ? a : -(*vsum_p);          // tanh(-inf) = -1 -> logit = -sum(v)
            float mx = a;
            #pragma unroll
            for (int m = 1; m < 32; m <<= 1) mx = fmaxf(mx, __shfl_xor(mx, m, 64));
            const float e = expf(a - mx);
            float s = e;
            #pragma unroll
            for (int m = 1; m < 32; m <<= 1) s += __shfl_xor(s, m, 64);
            if (lane < 32) ev[r] = e;
            if (lane == 0) {
                pms[(b * NCH_ + chunk) * 2] = mx;
                pms[(b * NCH_ + chunk) * 2 + 1] = s;
            }
        }
        __syncthreads();   // BAR2

        // ---- partial weighted sum from the bf16 As[p] tile ----
        f32x2 o = {0.f, 0.f};
        const int cu = tid * 2;
        #pragma unroll
        for (int t = 0; t < ROWS_; ++t) {
            const u32 h2 = *(const u32*)&As[p][t * MID_ + (cu ^ (t << 3))];
            const float w = ev[t];
            o[0] += w * bf2f(h2 & 0xFFFFu);
            o[1] += w * bf2f(h2 >> 16);
        }
        *(f32x2*)&po[(size_t)(b * NCH_ + chunk) * MID_ + cu] = o;
    }
    #undef ISSUE
    #undef CONVERT
}

// ---------------- combine: out[b][m] = sum_c w_c * o_c[m] ----------------
__global__ __launch_bounds__(256) void k_comb(const float* __restrict__ po,
                                              const float* __restrict__ pms,
                                              float* __restrict__ out) {
    __shared__ float wch[NCH_];
    const int b = blockIdx.x, tid = threadIdx.x;
    if (tid < 64) {
        const float mi = pms[(b * NCH_ + tid) * 2];
        const float si = pms[(b * NCH_ + tid) * 2 + 1];
        float M = mi;
        #pragma unroll
        for (int m = 1; m < 64; m <<= 1) M = fmaxf(M, __shfl_xor(M, m, 64));
        const float w = expf(mi - M);
        float D = si * w;
        #pragma unroll
        for (int m = 1; m < 64; m <<= 1) D += __shfl_xor(D, m, 64);
        wch[tid] = w / D;
    }
    __syncthreads();
    #pragma unroll
    for (int i = 0; i < 4; ++i) {
        const int mcol = i * 256 + tid;
        float s = 0.f;
        for (int c = 0; c < NCH_; ++c)
            s += wch[c] * po[((size_t)b * NCH_ + c) * MID_ + mcol];
        out[b * MID_ + mcol] = s;
    }
}

extern "C" void kernel_launch(void* const* d_in, const int* in_sizes, int n_in,
                              void* d_out, int out_size, void* d_ws, size_t ws_size,
                              hipStream_t stream) {
    const float* enc   = (const float*)d_in[0];
    const float* dec   = (const float*)d_in[1];
    const int*   masks = (const int*)d_in[2];
    const float* Ua_w  = (const float*)d_in[3];
    const float* Ua_b  = (const float*)d_in[4];
    const float* Wa_w  = (const float*)d_in[5];
    const float* v_w   = (const float*)d_in[6];
    float* out = (float*)d_out;

    char* ws = (char*)d_ws;
    float* enc_out = (float*)(ws + 0);        // 32 KB
    float* vsum    = (float*)(ws + 32768);    // 4 B (padded)
    u16*   wa16s   = (u16*)(ws + 65536);      // 512 KB
    float* pms     = (float*)(ws + 589824);   // 16 KB (2048 x {max,sum})
    float* po      = (float*)(ws + 606208);   // 8 MB  (2048 x 1024 partial sums)

    k_prep<<<dim3(289), dim3(256), 0, stream>>>(enc, Ua_w, Ua_b, Wa_w, v_w,
                                                enc_out, wa16s, vsum);
    k_fused<<<dim3(256), dim3(512), 0, stream>>>(dec, masks, enc_out, v_w, vsum,
                                                 wa16s, po, pms);
    k_comb<<<dim3(B_), dim3(256), 0, stream>>>(po, pms, out);
}

// Round 11
// 401.670 us; speedup vs baseline: 1.0335x; 1.0335x over previous
//
#include <hip/hip_runtime.h>
#include <hip/hip_bf16.h>

typedef unsigned short u16;
typedef unsigned int u32;
typedef __attribute__((ext_vector_type(2))) float f32x2;
typedef __attribute__((ext_vector_type(4))) float f32x4;
typedef __attribute__((ext_vector_type(4))) u16 u16x4;
typedef __attribute__((ext_vector_type(8))) u16 u16x8;
typedef __attribute__((ext_vector_type(8))) __bf16 bf16x8;

#define B_ 32
#define T_ 2048
#define MID_ 1024
#define TOPIC_ 512
#define H_ 256
#define ROWS_ 32
#define NCH_ (T_ / ROWS_)   // 64 chunks per batch
#define CPW_ 8              // chunks per workgroup (grid 256 = 1 WG/CU)

// fp32 -> bf16 RNE
static __device__ __forceinline__ u16 f2bf(float x) {
    u32 u = __float_as_uint(x);
    u = (u + 0x7FFFu + ((u >> 16) & 1u)) >> 16;
    return (u16)u;
}
static __device__ __forceinline__ float bf2f(u32 lo16) {
    return __uint_as_float(lo16 << 16);
}

// ---------------- merged prep ----------------
// blocks 0..255 : Wa row h=blk -> bf16 into layout
//   wa16s[ks:32][tt:16][kgrp:4][rl:16][j:8]  (u16 idx = ks*8192 + tt*512 + kgrp*128 + rl*8 + j)
// blocks 256..287 : enc_out[b][h];  block 288 : vsum.
__global__ __launch_bounds__(256) void k_prep(const float* __restrict__ enc,
                                              const float* __restrict__ Ua_w,
                                              const float* __restrict__ Ua_b,
                                              const float* __restrict__ Wa,
                                              const float* __restrict__ v_w,
                                              float* __restrict__ enc_out,
                                              u16* __restrict__ wa16s,
                                              float* __restrict__ vsum) {
    __shared__ float es[TOPIC_];
    const int blk = blockIdx.x, tid = threadIdx.x;
    if (blk < 256) {
        const int h = blk, k = tid * 4;
        f32x4 w = *(const f32x4*)(Wa + h * MID_ + k);
        u16x4 h4;
        h4[0] = f2bf(w[0]); h4[1] = f2bf(w[1]); h4[2] = f2bf(w[2]); h4[3] = f2bf(w[3]);
        const int tt = h >> 4, rl = h & 15;
        const int ks = k >> 5, kg = (k >> 3) & 3, j = k & 7;
        *(u16x4*)&wa16s[ks * 8192 + tt * 512 + kg * 128 + rl * 8 + j] = h4;
    } else if (blk < 288) {
        const int b = blk - 256;
        es[tid]       = enc[b * TOPIC_ + tid];
        es[tid + 256] = enc[b * TOPIC_ + 256 + tid];
        __syncthreads();
        const float* ua = Ua_w + (size_t)tid * TOPIC_;
        float s = Ua_b[tid];
        #pragma unroll 4
        for (int d = 0; d < TOPIC_; d += 4) {
            f32x4 u = *(const f32x4*)(ua + d);
            s += u[0] * es[d] + u[1] * es[d + 1] + u[2] * es[d + 2] + u[3] * es[d + 3];
        }
        enc_out[b * H_ + tid] = s;
    } else {
        if (tid < 64) {
            const int lane = tid;
            float s = v_w[lane] + v_w[lane + 64] + v_w[lane + 128] + v_w[lane + 192];
            #pragma unroll
            for (int m = 32; m; m >>= 1) s += __shfl_xor(s, m, 64);
            if (lane == 0) *vsum = s;
        }
    }
}

// ---------------- fused single-pass, As-double-buffered chunk pipeline ----------------
// grid 256 (1 WG/CU, persistent), 512 threads = 8 waves; each WG: 8 contiguous chunks
// of one batch row. Per iteration c: [BARt] [convert st -> As[p^1] (chunk c+1; its
// loads issued a full iteration ago -> wait ~0)] [issue st <- chunk c+2] [round-8
// barrier-free K-loop on As[p]] [partc, BAR1, softmax, BAR2, wsum from As[p]].
// All barrier vmcnt-drains are free (in-flight loads always ~1 K-loop old).
// NOTE r10 lesson: __launch_bounds__(512,N>=2) resolves to a 128-VGPR budget and
// SPILLS st[16] (FETCH 553MB/WRITE 157MB scratch). Plain (512) -> cap 512, ~170
// regs, no spill; grid=1 WG/CU sets occupancy anyway.
__global__ __launch_bounds__(512) void k_fused(const float* __restrict__ dec,
                                               const int* __restrict__ masks,
                                               const float* __restrict__ enc_out,
                                               const float* __restrict__ v_w,
                                               const float* __restrict__ vsum_p,
                                               const u16* __restrict__ wa16s,
                                               float* __restrict__ po,
                                               float* __restrict__ pms) {
    __shared__ __attribute__((aligned(16))) u16 As[2][ROWS_ * MID_];  // 128 KB
    __shared__ float partc[8][ROWS_];
    __shared__ float ev[ROWS_];

    const int tid = threadIdx.x;
    const int lane = tid & 63, wave = tid >> 6;
    const int rl = lane & 15, kgrp = lane >> 4;
    const int wg = blockIdx.x;                 // 0..255
    const int b = wg >> 3;                     // 8 WGs per batch row
    const int cbase = (wg & 7) * CPW_;         // contiguous 8-chunk span

    // enc/v per-lane registers (this wave's 32 cols)
    float encr[2], vr[2];
    #pragma unroll
    for (int ct = 0; ct < 2; ++ct) {
        const int h = wave * 32 + ct * 16 + rl;
        encr[ct] = enc_out[b * H_ + h];
        vr[ct] = v_w[h];
    }

    // constant bases (round-8 K-loop)
    const u16* bb = wa16s + wave * 1024 + kgrp * 128 + rl * 8;  // +ct*512 +ks*8192
    const int ar0 = rl * MID_,        k0 = rl << 3;
    const int ar1 = (16 + rl) * MID_, k1 = (16 + rl) << 3;
    const int kstart = wave * 4;               // per-wave rotated K order

    f32x4 st[16];   // staging regs: granule g = tid + i*512 (row=g>>7, colg=g&127)

    #define ISSUE(CI)                                                             \
        do {                                                                      \
            const float* base_ = dec + (size_t)(b * T_ + (CI) * ROWS_) * MID_;    \
            _Pragma("unroll") for (int i_ = 0; i_ < 8; ++i_) {                    \
                const int g_ = tid + i_ * 512;                                    \
                const float* sp_ = base_ + (size_t)(g_ >> 7) * MID_ + (g_ & 127) * 8; \
                st[2 * i_]     = *(const f32x4*)(sp_);                            \
                st[2 * i_ + 1] = *(const f32x4*)(sp_ + 4);                        \
            }                                                                     \
        } while (0)

    #define CONVERT(P)                                                            \
        do {                                                                      \
            _Pragma("unroll") for (int i_ = 0; i_ < 8; ++i_) {                    \
                const int g_ = tid + i_ * 512;                                    \
                const int row_ = g_ >> 7, colg_ = g_ & 127;                       \
                u16x8 h8_;                                                        \
                _Pragma("unroll") for (int e_ = 0; e_ < 4; ++e_) {                \
                    h8_[e_]     = f2bf(st[2 * i_][e_]);                           \
                    h8_[4 + e_] = f2bf(st[2 * i_ + 1][e_]);                       \
                }                                                                 \
                *(u16x8*)&As[P][row_ * MID_ + ((colg_ * 8) ^ (row_ << 3))] = h8_; \
            }                                                                     \
        } while (0)

    // ---- prologue: chunk 0 -> As[0]; chunk 1 loads in flight ----
    ISSUE(cbase);
    CONVERT(0);
    ISSUE(cbase + 1);

    #pragma unroll 1
    for (int c = 0; c < CPW_; ++c) {
        const int chunk = cbase + c;
        const int p = c & 1;
        const int grow = b * T_ + chunk * ROWS_;

        __syncthreads();   // BARt: As[p] converts visible; prior wsum of As[p^1] done

        // ---- convert chunk c+1 into the other buffer (st loads are 1 iter old) ----
        if (c + 1 < CPW_) CONVERT(p ^ 1);
        // ---- issue chunk c+2's staging loads (land during K-loop + epilogue) ----
        if (c + 2 < CPW_) ISSUE(cbase + c + 2);

        // ---- round-8 barrier-free fully-unrolled K-loop on As[p] ----
        f32x4 acc[2][2];
        const f32x4 z = {0.f, 0.f, 0.f, 0.f};
        acc[0][0] = z; acc[0][1] = z; acc[1][0] = z; acc[1][1] = z;

        bf16x8 br0[2], br1[2], br2[2], br3[2];
        {
            const int s0 = kstart, s1 = (kstart + 1) & 31;
            const int s2 = (kstart + 2) & 31, s3 = (kstart + 3) & 31;
            br0[0] = *(const bf16x8*)(bb + s0 * 8192);
            br0[1] = *(const bf16x8*)(bb + s0 * 8192 + 512);
            br1[0] = *(const bf16x8*)(bb + s1 * 8192);
            br1[1] = *(const bf16x8*)(bb + s1 * 8192 + 512);
            br2[0] = *(const bf16x8*)(bb + s2 * 8192);
            br2[1] = *(const bf16x8*)(bb + s2 * 8192 + 512);
            br3[0] = *(const bf16x8*)(bb + s3 * 8192);
            br3[1] = *(const bf16x8*)(bb + s3 * 8192 + 512);
        }
        bf16x8 afc0 = *(const bf16x8*)&As[p][ar0 + ((kstart * 32 + kgrp * 8) ^ k0)];
        bf16x8 afc1 = *(const bf16x8*)&As[p][ar1 + ((kstart * 32 + kgrp * 8) ^ k1)];

        #pragma unroll
        for (int i = 0; i < 32; ++i) {
            bf16x8 an0 = afc0, an1 = afc1;
            if (i < 31) {
                const int ksn = (kstart + i + 1) & 31;
                an0 = *(const bf16x8*)&As[p][ar0 + ((ksn * 32 + kgrp * 8) ^ k0)];
                an1 = *(const bf16x8*)&As[p][ar1 + ((ksn * 32 + kgrp * 8) ^ k1)];
            }
            {
                bf16x8* brc = ((i & 3) == 0) ? br0 : ((i & 3) == 1) ? br1
                             : ((i & 3) == 2) ? br2 : br3;
                acc[0][0] = __builtin_amdgcn_mfma_f32_16x16x32_bf16(afc0, brc[0], acc[0][0], 0, 0, 0);
                acc[1][0] = __builtin_amdgcn_mfma_f32_16x16x32_bf16(afc1, brc[0], acc[1][0], 0, 0, 0);
                acc[0][1] = __builtin_amdgcn_mfma_f32_16x16x32_bf16(afc0, brc[1], acc[0][1], 0, 0, 0);
                acc[1][1] = __builtin_amdgcn_mfma_f32_16x16x32_bf16(afc1, brc[1], acc[1][1], 0, 0, 0);
                if (i < 28) {
                    const int ksp = (kstart + i + 4) & 31;
                    brc[0] = *(const bf16x8*)(bb + ksp * 8192);
                    brc[1] = *(const bf16x8*)(bb + ksp * 8192 + 512);
                }
            }
            afc0 = an0; afc1 = an1;
        }

        // ---- logits partials ----
        float part[2][4];
        #pragma unroll
        for (int rt = 0; rt < 2; ++rt)
            #pragma unroll
            for (int j = 0; j < 4; ++j) {
                float pp = 0.f;
                #pragma unroll
                for (int ct = 0; ct < 2; ++ct)
                    pp += vr[ct] * tanhf(encr[ct] + acc[rt][ct][j]);
                part[rt][j] = pp;
            }
        #pragma unroll
        for (int m = 1; m < 16; m <<= 1)
            #pragma unroll
            for (int rt = 0; rt < 2; ++rt)
                #pragma unroll
                for (int j = 0; j < 4; ++j)
                    part[rt][j] += __shfl_xor(part[rt][j], m, 64);
        if (rl == 0) {
            #pragma unroll
            for (int rt = 0; rt < 2; ++rt)
                #pragma unroll
                for (int j = 0; j < 4; ++j)
                    partc[wave][rt * 16 + kgrp * 4 + j] = part[rt][j];
        }
        __syncthreads();   // BAR1 (st loads for c+2 are ~K-loop old -> drain free)

        // ---- chunk softmax (32 rows; wave 0) ----
        if (wave == 0) {
            const int r = lane & 31;
            float a = 0.f;
            #pragma unroll
            for (int w = 0; w < 8; ++w) a += partc[w][r];
            const int mk = masks[grow + r];
            a = mk ? a : -(*vsum_p);          // tanh(-inf) = -1 -> logit = -sum(v)
            float mx = a;
            #pragma unroll
            for (int m = 1; m < 32; m <<= 1) mx = fmaxf(mx, __shfl_xor(mx, m, 64));
            const float e = expf(a - mx);
            float s = e;
            #pragma unroll
            for (int m = 1; m < 32; m <<= 1) s += __shfl_xor(s, m, 64);
            if (lane < 32) ev[r] = e;
            if (lane == 0) {
                pms[(b * NCH_ + chunk) * 2] = mx;
                pms[(b * NCH_ + chunk) * 2 + 1] = s;
            }
        }
        __syncthreads();   // BAR2

        // ---- partial weighted sum from the bf16 As[p] tile ----
        f32x2 o = {0.f, 0.f};
        const int cu = tid * 2;
        #pragma unroll
        for (int t = 0; t < ROWS_; ++t) {
            const u32 h2 = *(const u32*)&As[p][t * MID_ + (cu ^ (t << 3))];
            const float w = ev[t];
            o[0] += w * bf2f(h2 & 0xFFFFu);
            o[1] += w * bf2f(h2 >> 16);
        }
        *(f32x2*)&po[(size_t)(b * NCH_ + chunk) * MID_ + cu] = o;
    }
    #undef ISSUE
    #undef CONVERT
}

// ---------------- combine: out[b][m] = sum_c w_c * o_c[m] ----------------
__global__ __launch_bounds__(256) void k_comb(const float* __restrict__ po,
                                              const float* __restrict__ pms,
                                              float* __restrict__ out) {
    __shared__ float wch[NCH_];
    const int b = blockIdx.x, tid = threadIdx.x;
    if (tid < 64) {
        const float mi = pms[(b * NCH_ + tid) * 2];
        const float si = pms[(b * NCH_ + tid) * 2 + 1];
        float M = mi;
        #pragma unroll
        for (int m = 1; m < 64; m <<= 1) M = fmaxf(M, __shfl_xor(M, m, 64));
        const float w = expf(mi - M);
        float D = si * w;
        #pragma unroll
        for (int m = 1; m < 64; m <<= 1) D += __shfl_xor(D, m, 64);
        wch[tid] = w / D;
    }
    __syncthreads();
    #pragma unroll
    for (int i = 0; i < 4; ++i) {
        const int mcol = i * 256 + tid;
        float s = 0.f;
        for (int c = 0; c < NCH_; ++c)
            s += wch[c] * po[((size_t)b * NCH_ + c) * MID_ + mcol];
        out[b * MID_ + mcol] = s;
    }
}

extern "C" void kernel_launch(void* const* d_in, const int* in_sizes, int n_in,
                              void* d_out, int out_size, void* d_ws, size_t ws_size,
                              hipStream_t stream) {
    const float* enc   = (const float*)d_in[0];
    const float* dec   = (const float*)d_in[1];
    const int*   masks = (const int*)d_in[2];
    const float* Ua_w  = (const float*)d_in[3];
    const float* Ua_b  = (const float*)d_in[4];
    const float* Wa_w  = (const float*)d_in[5];
    const float* v_w   = (const float*)d_in[6];
    float* out = (float*)d_out;

    char* ws = (char*)d_ws;
    float* enc_out = (float*)(ws + 0);        // 32 KB
    float* vsum    = (float*)(ws + 32768);    // 4 B (padded)
    u16*   wa16s   = (u16*)(ws + 65536);      // 512 KB
    float* pms     = (float*)(ws + 589824);   // 16 KB (2048 x {max,sum})
    float* po      = (float*)(ws + 606208);   // 8 MB  (2048 x 1024 partial sums)

    k_prep<<<dim3(289), dim3(256), 0, stream>>>(enc, Ua_w, Ua_b, Wa_w, v_w,
                                                enc_out, wa16s, vsum);
    k_fused<<<dim3(256), dim3(512), 0, stream>>>(dec, masks, enc_out, v_w, vsum,
                                                 wa16s, po, pms);
    k_comb<<<dim3(B_), dim3(256), 0, stream>>>(po, pms, out);
}

// Round 12
// 345.733 us; speedup vs baseline: 1.2007x; 1.1618x over previous
//
#include <hip/hip_runtime.h>
#include <hip/hip_bf16.h>

typedef unsigned short u16;
typedef unsigned int u32;
typedef __attribute__((ext_vector_type(2))) float f32x2;
typedef __attribute__((ext_vector_type(4))) float f32x4;
typedef __attribute__((ext_vector_type(4))) u16 u16x4;
typedef __attribute__((ext_vector_type(8))) u16 u16x8;
typedef __attribute__((ext_vector_type(8))) __bf16 bf16x8;

#define B_ 32
#define T_ 2048
#define MID_ 1024
#define TOPIC_ 512
#define H_ 256
#define ROWS_ 32
#define NCH_ (T_ / ROWS_)   // 64 chunks per batch
#define CPW_ 8              // chunks per workgroup (grid 256 = 1 WG/CU)

// fp32 -> bf16 RNE
static __device__ __forceinline__ u16 f2bf(float x) {
    u32 u = __float_as_uint(x);
    u = (u + 0x7FFFu + ((u >> 16) & 1u)) >> 16;
    return (u16)u;
}
static __device__ __forceinline__ float bf2f(u32 lo16) {
    return __uint_as_float(lo16 << 16);
}

// ---------------- merged prep ----------------
// blocks 0..255 : Wa row h=blk -> bf16 into layout
//   wa16s[ks:32][tt:16][kgrp:4][rl:16][j:8]  (u16 idx = ks*8192 + tt*512 + kgrp*128 + rl*8 + j)
// blocks 256..287 : enc_out[b][h];  block 288 : vsum.
__global__ __launch_bounds__(256) void k_prep(const float* __restrict__ enc,
                                              const float* __restrict__ Ua_w,
                                              const float* __restrict__ Ua_b,
                                              const float* __restrict__ Wa,
                                              const float* __restrict__ v_w,
                                              float* __restrict__ enc_out,
                                              u16* __restrict__ wa16s,
                                              float* __restrict__ vsum) {
    __shared__ float es[TOPIC_];
    const int blk = blockIdx.x, tid = threadIdx.x;
    if (blk < 256) {
        const int h = blk, k = tid * 4;
        f32x4 w = *(const f32x4*)(Wa + h * MID_ + k);
        u16x4 h4;
        h4[0] = f2bf(w[0]); h4[1] = f2bf(w[1]); h4[2] = f2bf(w[2]); h4[3] = f2bf(w[3]);
        const int tt = h >> 4, rl = h & 15;
        const int ks = k >> 5, kg = (k >> 3) & 3, j = k & 7;
        *(u16x4*)&wa16s[ks * 8192 + tt * 512 + kg * 128 + rl * 8 + j] = h4;
    } else if (blk < 288) {
        const int b = blk - 256;
        es[tid]       = enc[b * TOPIC_ + tid];
        es[tid + 256] = enc[b * TOPIC_ + 256 + tid];
        __syncthreads();
        const float* ua = Ua_w + (size_t)tid * TOPIC_;
        float s = Ua_b[tid];
        #pragma unroll 4
        for (int d = 0; d < TOPIC_; d += 4) {
            f32x4 u = *(const f32x4*)(ua + d);
            s += u[0] * es[d] + u[1] * es[d + 1] + u[2] * es[d + 2] + u[3] * es[d + 3];
        }
        enc_out[b * H_ + tid] = s;
    } else {
        if (tid < 64) {
            const int lane = tid;
            float s = v_w[lane] + v_w[lane + 64] + v_w[lane + 128] + v_w[lane + 192];
            #pragma unroll
            for (int m = 32; m; m >>= 1) s += __shfl_xor(s, m, 64);
            if (lane == 0) *vsum = s;
        }
    }
}

// ---------------- fused single-pass, half-chunk-pipelined (fits 128 VGPR) ----------------
// grid 256 (1 WG/CU persistent), 512 threads = 8 waves; each WG: 8 contiguous chunks.
// r9-r11 lesson: hipcc caps 512-thread kernels at 128 VGPR (even plain (512)) -> the
// full-chunk st[16] (64 regs) ALWAYS spills. Fix: pipeline at HALF-chunk granularity
// with ONE st[8] buffer (32 regs) reused twice per iteration:
//   BARt -> convert H0(c+1) (landed) + issue H1(c+1) -> K-loop (H1 lands under it)
//        -> convert H1(c+1) -> partials/BAR1/softmax/BAR2 -> issue H0(c+2) -> wsum.
// As[2] double-buffer (128 KB); barrier-free unrolled K-loop identical to r8.
__global__ __launch_bounds__(512) void k_fused(const float* __restrict__ dec,
                                               const int* __restrict__ masks,
                                               const float* __restrict__ enc_out,
                                               const float* __restrict__ v_w,
                                               const float* __restrict__ vsum_p,
                                               const u16* __restrict__ wa16s,
                                               float* __restrict__ po,
                                               float* __restrict__ pms) {
    __shared__ __attribute__((aligned(16))) u16 As[2][ROWS_ * MID_];  // 128 KB
    __shared__ float partc[8][ROWS_];
    __shared__ float ev[ROWS_];

    const int tid = threadIdx.x;
    const int lane = tid & 63, wave = tid >> 6;
    const int rl = lane & 15, kgrp = lane >> 4;
    const int wg = blockIdx.x;                 // 0..255
    const int b = wg >> 3;                     // 8 WGs per batch row
    const int cbase = (wg & 7) * CPW_;         // contiguous 8-chunk span

    // enc/v per-lane registers (this wave's 32 cols)
    float encr[2], vr[2];
    #pragma unroll
    for (int ct = 0; ct < 2; ++ct) {
        const int h = wave * 32 + ct * 16 + rl;
        encr[ct] = enc_out[b * H_ + h];
        vr[ct] = v_w[h];
    }

    // constant bases (round-8 K-loop)
    const u16* bb = wa16s + wave * 1024 + kgrp * 128 + rl * 8;  // +ct*512 +ks*8192
    const int ar0 = rl * MID_,        k0 = rl << 3;
    const int ar1 = (16 + rl) * MID_, k1 = (16 + rl) << 3;
    const int kstart = wave * 4;               // per-wave rotated K order

    f32x4 st[8];   // HALF-chunk staging: 4 granules of 32B per thread (32 VGPR)

    // granule g = tid + i*512 (i 0..3): row16 = g>>7 (0..15), coln = g&127 (8-f32 col)
    #define ISSUE_H(CI, HH)                                                       \
        do {                                                                      \
            const float* base_ = dec + (size_t)(b * T_ + (CI) * ROWS_ + (HH) * 16) * MID_; \
            _Pragma("unroll") for (int i_ = 0; i_ < 4; ++i_) {                    \
                const int g_ = tid + i_ * 512;                                    \
                const float* sp_ = base_ + (size_t)(g_ >> 7) * MID_ + (g_ & 127) * 8; \
                st[2 * i_]     = *(const f32x4*)(sp_);                            \
                st[2 * i_ + 1] = *(const f32x4*)(sp_ + 4);                        \
            }                                                                     \
        } while (0)

    #define CONVERT_H(P, HH)                                                      \
        do {                                                                      \
            _Pragma("unroll") for (int i_ = 0; i_ < 4; ++i_) {                    \
                const int g_ = tid + i_ * 512;                                    \
                const int row_ = (g_ >> 7) + (HH) * 16, coln_ = g_ & 127;         \
                u16x8 h8_;                                                        \
                _Pragma("unroll") for (int e_ = 0; e_ < 4; ++e_) {                \
                    h8_[e_]     = f2bf(st[2 * i_][e_]);                           \
                    h8_[4 + e_] = f2bf(st[2 * i_ + 1][e_]);                       \
                }                                                                 \
                *(u16x8*)&As[P][row_ * MID_ + ((coln_ * 8) ^ (row_ << 3))] = h8_; \
            }                                                                     \
        } while (0)

    // ---- prologue: chunk cbase -> As[0]; H0(cbase+1) in flight ----
    ISSUE_H(cbase, 0);
    CONVERT_H(0, 0);
    ISSUE_H(cbase, 1);
    CONVERT_H(0, 1);
    ISSUE_H(cbase + 1, 0);

    #pragma unroll 1
    for (int c = 0; c < CPW_; ++c) {
        const int chunk = cbase + c;
        const int p = c & 1;
        const int grow = b * T_ + chunk * ROWS_;

        __syncthreads();   // BARt: As[p] complete; prior wsum of As[p^1] done

        // ---- convert H0(c+1) (loads ~1 iter old); issue H1(c+1) (lands in K-loop) ----
        if (c + 1 < CPW_) {
            CONVERT_H(p ^ 1, 0);
            ISSUE_H(cbase + c + 1, 1);
        }

        // ---- round-8 barrier-free fully-unrolled K-loop on As[p] ----
        f32x4 acc[2][2];
        const f32x4 z = {0.f, 0.f, 0.f, 0.f};
        acc[0][0] = z; acc[0][1] = z; acc[1][0] = z; acc[1][1] = z;

        bf16x8 br0[2], br1[2], br2[2], br3[2];
        {
            const int s0 = kstart, s1 = (kstart + 1) & 31;
            const int s2 = (kstart + 2) & 31, s3 = (kstart + 3) & 31;
            br0[0] = *(const bf16x8*)(bb + s0 * 8192);
            br0[1] = *(const bf16x8*)(bb + s0 * 8192 + 512);
            br1[0] = *(const bf16x8*)(bb + s1 * 8192);
            br1[1] = *(const bf16x8*)(bb + s1 * 8192 + 512);
            br2[0] = *(const bf16x8*)(bb + s2 * 8192);
            br2[1] = *(const bf16x8*)(bb + s2 * 8192 + 512);
            br3[0] = *(const bf16x8*)(bb + s3 * 8192);
            br3[1] = *(const bf16x8*)(bb + s3 * 8192 + 512);
        }
        bf16x8 afc0 = *(const bf16x8*)&As[p][ar0 + ((kstart * 32 + kgrp * 8) ^ k0)];
        bf16x8 afc1 = *(const bf16x8*)&As[p][ar1 + ((kstart * 32 + kgrp * 8) ^ k1)];

        #pragma unroll
        for (int i = 0; i < 32; ++i) {
            bf16x8 an0 = afc0, an1 = afc1;
            if (i < 31) {
                const int ksn = (kstart + i + 1) & 31;
                an0 = *(const bf16x8*)&As[p][ar0 + ((ksn * 32 + kgrp * 8) ^ k0)];
                an1 = *(const bf16x8*)&As[p][ar1 + ((ksn * 32 + kgrp * 8) ^ k1)];
            }
            {
                bf16x8* brc = ((i & 3) == 0) ? br0 : ((i & 3) == 1) ? br1
                             : ((i & 3) == 2) ? br2 : br3;
                acc[0][0] = __builtin_amdgcn_mfma_f32_16x16x32_bf16(afc0, brc[0], acc[0][0], 0, 0, 0);
                acc[1][0] = __builtin_amdgcn_mfma_f32_16x16x32_bf16(afc1, brc[0], acc[1][0], 0, 0, 0);
                acc[0][1] = __builtin_amdgcn_mfma_f32_16x16x32_bf16(afc0, brc[1], acc[0][1], 0, 0, 0);
                acc[1][1] = __builtin_amdgcn_mfma_f32_16x16x32_bf16(afc1, brc[1], acc[1][1], 0, 0, 0);
                if (i < 28) {
                    const int ksp = (kstart + i + 4) & 31;
                    brc[0] = *(const bf16x8*)(bb + ksp * 8192);
                    brc[1] = *(const bf16x8*)(bb + ksp * 8192 + 512);
                }
            }
            afc0 = an0; afc1 = an1;
        }

        // ---- convert H1(c+1): its loads landed under the K-loop ----
        if (c + 1 < CPW_) CONVERT_H(p ^ 1, 1);

        // ---- logits partials ----
        float part[2][4];
        #pragma unroll
        for (int rt = 0; rt < 2; ++rt)
            #pragma unroll
            for (int j = 0; j < 4; ++j) {
                float pp = 0.f;
                #pragma unroll
                for (int ct = 0; ct < 2; ++ct)
                    pp += vr[ct] * tanhf(encr[ct] + acc[rt][ct][j]);
                part[rt][j] = pp;
            }
        #pragma unroll
        for (int m = 1; m < 16; m <<= 1)
            #pragma unroll
            for (int rt = 0; rt < 2; ++rt)
                #pragma unroll
                for (int j = 0; j < 4; ++j)
                    part[rt][j] += __shfl_xor(part[rt][j], m, 64);
        if (rl == 0) {
            #pragma unroll
            for (int rt = 0; rt < 2; ++rt)
                #pragma unroll
                for (int j = 0; j < 4; ++j)
                    partc[wave][rt * 16 + kgrp * 4 + j] = part[rt][j];
        }
        __syncthreads();   // BAR1

        // ---- chunk softmax (32 rows; wave 0) ----
        if (wave == 0) {
            const int r = lane & 31;
            float a = 0.f;
            #pragma unroll
            for (int w = 0; w < 8; ++w) a += partc[w][r];
            const int mk = masks[grow + r];
            a = mk ? a : -(*vsum_p);          // tanh(-inf) = -1 -> logit = -sum(v)
            float mx = a;
            #pragma unroll
            for (int m = 1; m < 32; m <<= 1) mx = fmaxf(mx, __shfl_xor(mx, m, 64));
            const float e = expf(a - mx);
            float s = e;
            #pragma unroll
            for (int m = 1; m < 32; m <<= 1) s += __shfl_xor(s, m, 64);
            if (lane < 32) ev[r] = e;
            if (lane == 0) {
                pms[(b * NCH_ + chunk) * 2] = mx;
                pms[(b * NCH_ + chunk) * 2 + 1] = s;
            }
        }
        __syncthreads();   // BAR2

        // ---- issue H0(c+2): hidden under wsum until next BARt ----
        if (c + 2 < CPW_) ISSUE_H(cbase + c + 2, 0);

        // ---- partial weighted sum from the bf16 As[p] tile ----
        f32x2 o = {0.f, 0.f};
        const int cu = tid * 2;
        #pragma unroll
        for (int t = 0; t < ROWS_; ++t) {
            const u32 h2 = *(const u32*)&As[p][t * MID_ + (cu ^ (t << 3))];
            const float w = ev[t];
            o[0] += w * bf2f(h2 & 0xFFFFu);
            o[1] += w * bf2f(h2 >> 16);
        }
        *(f32x2*)&po[(size_t)(b * NCH_ + chunk) * MID_ + cu] = o;
    }
    #undef ISSUE_H
    #undef CONVERT_H
}

// ---------------- combine: out[b][m] = sum_c w_c * o_c[m] ----------------
__global__ __launch_bounds__(256) void k_comb(const float* __restrict__ po,
                                              const float* __restrict__ pms,
                                              float* __restrict__ out) {
    __shared__ float wch[NCH_];
    const int b = blockIdx.x, tid = threadIdx.x;
    if (tid < 64) {
        const float mi = pms[(b * NCH_ + tid) * 2];
        const float si = pms[(b * NCH_ + tid) * 2 + 1];
        float M = mi;
        #pragma unroll
        for (int m = 1; m < 64; m <<= 1) M = fmaxf(M, __shfl_xor(M, m, 64));
        const float w = expf(mi - M);
        float D = si * w;
        #pragma unroll
        for (int m = 1; m < 64; m <<= 1) D += __shfl_xor(D, m, 64);
        wch[tid] = w / D;
    }
    __syncthreads();
    #pragma unroll
    for (int i = 0; i < 4; ++i) {
        const int mcol = i * 256 + tid;
        float s = 0.f;
        for (int c = 0; c < NCH_; ++c)
            s += wch[c] * po[((size_t)b * NCH_ + c) * MID_ + mcol];
        out[b * MID_ + mcol] = s;
    }
}

extern "C" void kernel_launch(void* const* d_in, const int* in_sizes, int n_in,
                              void* d_out, int out_size, void* d_ws, size_t ws_size,
                              hipStream_t stream) {
    const float* enc   = (const float*)d_in[0];
    const float* dec   = (const float*)d_in[1];
    const int*   masks = (const int*)d_in[2];
    const float* Ua_w  = (const float*)d_in[3];
    const float* Ua_b  = (const float*)d_in[4];
    const float* Wa_w  = (const float*)d_in[5];
    const float* v_w   = (const float*)d_in[6];
    float* out = (float*)d_out;

    char* ws = (char*)d_ws;
    float* enc_out = (float*)(ws + 0);        // 32 KB
    float* vsum    = (float*)(ws + 32768);    // 4 B (padded)
    u16*   wa16s   = (u16*)(ws + 65536);      // 512 KB
    float* pms     = (float*)(ws + 589824);   // 16 KB (2048 x {max,sum})
    float* po      = (float*)(ws + 606208);   // 8 MB  (2048 x 1024 partial sums)

    k_prep<<<dim3(289), dim3(256), 0, stream>>>(enc, Ua_w, Ua_b, Wa_w, v_w,
                                                enc_out, wa16s, vsum);
    k_fused<<<dim3(256), dim3(512), 0, stream>>>(dec, masks, enc_out, v_w, vsum,
                                                 wa16s, po, pms);
    k_comb<<<dim3(B_), dim3(256), 0, stream>>>(po, pms, out);
}